// Round 3
// baseline (1460.179 us; speedup 1.0000x reference)
//
#include <hip/hip_runtime.h>

// ---------------------------------------------------------------------------
// HeteroSAGE, linked-list pull:
//   build per-dst linked lists (coalesced 8B ns[e]={next,src} + atomicExch head),
//   project neighbor features to bf16 h, then pull kernels traverse chains,
//   fusing root matvec + mean + relu + layer-2 dot products. Layer-2 edge
//   term is a scalar push-scatter (L2-resident atomics).
// ---------------------------------------------------------------------------

typedef unsigned short ushort_t;

__device__ inline ushort_t f2bf(float f) {
    unsigned u = __float_as_uint(f);
    unsigned r = (u + 0x7FFFu + ((u >> 16) & 1u)) >> 16;
    return (ushort_t)r;
}
__device__ inline float bf2f_lo(unsigned u) { return __uint_as_float(u << 16); }
__device__ inline float bf2f_hi(unsigned u) { return __uint_as_float(u & 0xFFFF0000u); }

__global__ void prep_weights(
    const float* __restrict__ Wl1_pp, const float* __restrict__ Wr1_pp,
    const float* __restrict__ Wl1_ap, const float* __restrict__ Wr1_ap,
    const float* __restrict__ Wl1_pa, const float* __restrict__ Wr1_pa,
    const float* __restrict__ bl1_pp, const float* __restrict__ bl1_ap,
    const float* __restrict__ bl1_pa,
    const float* __restrict__ Wl2_pp, const float* __restrict__ bl2_pp,
    const float* __restrict__ Wr2_pp,
    const float* __restrict__ Wl2_ap, const float* __restrict__ bl2_ap,
    const float* __restrict__ Wr2_ap,
    const float* __restrict__ W_lin, const float* __restrict__ b_lin,
    float* __restrict__ Wn_p,   // 64 x 64: [Wl1_pp | Wl1_pa]
    float* __restrict__ Wn_a,   // 64 x 32: [Wl1_ap]
    float* __restrict__ Wr_p,   // 64 x 32: Wr1_pp + Wr1_ap
    float* __restrict__ Wr_a,   // 64 x 32: Wr1_pa
    float* __restrict__ bias_p, // 32: bl1_pp + bl1_ap
    float* __restrict__ bias_a, // 32: bl1_pa
    float* __restrict__ vv)     // [0:32) v_pp  [32:64) v_r  [64] c2  [96:128) v_ap
{
    int t = threadIdx.x;
    for (int idx = t; idx < 64 * 64; idx += 256) {
        int i = idx / 64, j = idx % 64;
        Wn_p[idx] = (j < 32) ? Wl1_pp[i * 32 + j] : Wl1_pa[i * 32 + (j - 32)];
    }
    for (int idx = t; idx < 64 * 32; idx += 256) {
        Wn_a[idx] = Wl1_ap[idx];
        Wr_p[idx] = Wr1_pp[idx] + Wr1_ap[idx];
        Wr_a[idx] = Wr1_pa[idx];
    }
    if (t < 32) {
        bias_p[t] = bl1_pp[t] + bl1_ap[t];
        bias_a[t] = bl1_pa[t];
        float vpp = 0.f, vr = 0.f, vap = 0.f;
        for (int j = 0; j < 32; ++j) {
            float wl = W_lin[j];
            vpp += Wl2_pp[t * 32 + j] * wl;
            vr  += (Wr2_pp[t * 32 + j] + Wr2_ap[t * 32 + j]) * wl;
            vap += Wl2_ap[t * 32 + j] * wl;
        }
        vv[t] = vpp; vv[32 + t] = vr; vv[96 + t] = vap;
    }
    if (t == 0) {
        float c = b_lin[0];
        for (int j = 0; j < 32; ++j) c += (bl2_pp[j] + bl2_ap[j]) * W_lin[j];
        vv[64] = c;
    }
}

// linked-list build: ns[e] = {next = old head[dst], src}; fully coalesced 8B write.
__global__ void build_ll(const int* __restrict__ src, const int* __restrict__ dst,
                         int* __restrict__ head, int2* __restrict__ ns, int E)
{
    int e = blockIdx.x * blockDim.x + threadIdx.x;
    if (e < E) {
        int s = src[e], d = dst[e];
        int old = atomicExch(&head[d], e);
        ns[e] = make_int2(old, s);
    }
}

// neighbor projections: paper -> h_pp (32) and h_pa (32), bf16.
__global__ void proj_paper(const float* __restrict__ x, const float* __restrict__ Wn,
                           ushort_t* __restrict__ h_pp, ushort_t* __restrict__ h_pa, int N)
{
    __shared__ float Wlds[64 * 64];
    for (int i = threadIdx.x; i < 64 * 64; i += 256) Wlds[i] = Wn[i];
    __syncthreads();
    int n = blockIdx.x * 8 + (threadIdx.x >> 5);
    int c = threadIdx.x & 31;
    if (n < N) {
        const float* xr = x + (size_t)n * 64;
        float a0 = 0.f, a1 = 0.f;
#pragma unroll
        for (int i = 0; i < 64; ++i) {
            float xv = xr[i];
            a0 += xv * Wlds[i * 64 + c];
            a1 += xv * Wlds[i * 64 + 32 + c];
        }
        h_pp[(size_t)n * 32 + c] = f2bf(a0);
        h_pa[(size_t)n * 32 + c] = f2bf(a1);
    }
}

__global__ void proj_author(const float* __restrict__ x, const float* __restrict__ Wn,
                            ushort_t* __restrict__ h_ap, int N)
{
    __shared__ float Wlds[64 * 32];
    for (int i = threadIdx.x; i < 64 * 32; i += 256) Wlds[i] = Wn[i];
    __syncthreads();
    int n = blockIdx.x * 8 + (threadIdx.x >> 5);
    int c = threadIdx.x & 31;
    if (n < N) {
        const float* xr = x + (size_t)n * 64;
        float a0 = 0.f;
#pragma unroll
        for (int i = 0; i < 64; ++i) a0 += xr[i] * Wlds[i * 32 + c];
        h_ap[(size_t)n * 32 + c] = f2bf(a0);
    }
}

// 16 lanes/node, 2 cols/lane. Fuses root matvec (x,W in LDS) + interleaved
// pp/ap chain traversal + mean + relu + layer-2 dots. Writes s_pp, inv_pp,
// inv_ap, and the out base term.
__global__ void pull_paper(const float* __restrict__ x,
                           const ushort_t* __restrict__ h_pp, const ushort_t* __restrict__ h_ap,
                           const int* __restrict__ head_pp, const int2* __restrict__ ns_pp,
                           const int* __restrict__ head_ap, const int2* __restrict__ ns_ap,
                           const float* __restrict__ Wr, const float* __restrict__ bias,
                           const float* __restrict__ vv,
                           float* __restrict__ s_pp, float* __restrict__ inv_pp,
                           float* __restrict__ inv_ap, float* __restrict__ out, int N)
{
    __shared__ float Wlds[64 * 32];
    __shared__ float xlds[16 * 65];
    __shared__ float v0[32], v1[32], blds[32];
    __shared__ float c2s;
    for (int i = threadIdx.x; i < 64 * 32; i += 256) Wlds[i] = Wr[i];
    if (threadIdx.x < 32) {
        v0[threadIdx.x] = vv[threadIdx.x];
        v1[threadIdx.x] = vv[32 + threadIdx.x];
        blds[threadIdx.x] = bias[threadIdx.x];
    }
    if (threadIdx.x == 0) c2s = vv[64];
    int base = blockIdx.x * 16;
    {   // stage 16 x-rows: 256 threads x float4, coalesced
        int t4 = threadIdx.x * 4;
        int row = t4 >> 6, col = t4 & 63;
        int nn = base + row;
        float4 xv = (nn < N) ? *(const float4*)(x + (size_t)nn * 64 + col)
                             : make_float4(0.f, 0.f, 0.f, 0.f);
        float* dstp = &xlds[row * 65 + col];
        dstp[0] = xv.x; dstp[1] = xv.y; dstp[2] = xv.z; dstp[3] = xv.w;
    }
    __syncthreads();
    int g = threadIdx.x >> 4, c = threadIdx.x & 15;
    int n = base + g;
    if (n >= N) return;
    float r0 = blds[2 * c], r1 = blds[2 * c + 1];
#pragma unroll
    for (int i = 0; i < 64; ++i) {
        float xv = xlds[g * 65 + i];
        r0 += xv * Wlds[i * 32 + 2 * c];
        r1 += xv * Wlds[i * 32 + 2 * c + 1];
    }
    int e1 = head_pp[n], e2 = head_ap[n];
    int k1 = 0, k2 = 0;
    float a0 = 0.f, a1 = 0.f, b0 = 0.f, b1 = 0.f;
    while (e1 >= 0 || e2 >= 0) {
        if (e1 >= 0) {
            int2 p = ns_pp[e1];
            unsigned hv = *(const unsigned*)(h_pp + ((size_t)p.y * 32 + 2 * c));
            a0 += bf2f_lo(hv); a1 += bf2f_hi(hv);
            ++k1; e1 = p.x;
        }
        if (e2 >= 0) {
            int2 p = ns_ap[e2];
            unsigned hv = *(const unsigned*)(h_ap + ((size_t)p.y * 32 + 2 * c));
            b0 += bf2f_lo(hv); b1 += bf2f_hi(hv);
            ++k2; e2 = p.x;
        }
    }
    float ipp = 1.0f / fmaxf((float)k1, 1.0f);
    float iap = 1.0f / fmaxf((float)k2, 1.0f);
    float p0 = fmaxf(r0 + a0 * ipp + b0 * iap, 0.f);
    float p1 = fmaxf(r1 + a1 * ipp + b1 * iap, 0.f);
    float d0 = p0 * v0[2 * c] + p1 * v0[2 * c + 1];
    float d1 = p0 * v1[2 * c] + p1 * v1[2 * c + 1];
#pragma unroll
    for (int off = 1; off < 16; off <<= 1) {
        d0 += __shfl_xor(d0, off);
        d1 += __shfl_xor(d1, off);
    }
    if (c == 0) {
        s_pp[n] = d0;
        out[n] = d1 + c2s;
        inv_pp[n] = ipp;
        inv_ap[n] = iap;
    }
}

__global__ void pull_author(const float* __restrict__ x, const ushort_t* __restrict__ h_pa,
                            const int* __restrict__ head_pa, const int2* __restrict__ ns_pa,
                            const float* __restrict__ Wr, const float* __restrict__ bias,
                            const float* __restrict__ vv, float* __restrict__ s_ap, int N)
{
    __shared__ float Wlds[64 * 32];
    __shared__ float xlds[16 * 65];
    __shared__ float v0[32], blds[32];
    for (int i = threadIdx.x; i < 64 * 32; i += 256) Wlds[i] = Wr[i];
    if (threadIdx.x < 32) {
        v0[threadIdx.x] = vv[96 + threadIdx.x];
        blds[threadIdx.x] = bias[threadIdx.x];
    }
    int base = blockIdx.x * 16;
    {
        int t4 = threadIdx.x * 4;
        int row = t4 >> 6, col = t4 & 63;
        int nn = base + row;
        float4 xv = (nn < N) ? *(const float4*)(x + (size_t)nn * 64 + col)
                             : make_float4(0.f, 0.f, 0.f, 0.f);
        float* dstp = &xlds[row * 65 + col];
        dstp[0] = xv.x; dstp[1] = xv.y; dstp[2] = xv.z; dstp[3] = xv.w;
    }
    __syncthreads();
    int g = threadIdx.x >> 4, c = threadIdx.x & 15;
    int n = base + g;
    if (n >= N) return;
    float r0 = blds[2 * c], r1 = blds[2 * c + 1];
#pragma unroll
    for (int i = 0; i < 64; ++i) {
        float xv = xlds[g * 65 + i];
        r0 += xv * Wlds[i * 32 + 2 * c];
        r1 += xv * Wlds[i * 32 + 2 * c + 1];
    }
    int e1 = head_pa[n];
    int k1 = 0;
    float a0 = 0.f, a1 = 0.f;
    while (e1 >= 0) {
        int2 p = ns_pa[e1];
        unsigned hv = *(const unsigned*)(h_pa + ((size_t)p.y * 32 + 2 * c));
        a0 += bf2f_lo(hv); a1 += bf2f_hi(hv);
        ++k1; e1 = p.x;
    }
    float ip = 1.0f / fmaxf((float)k1, 1.0f);
    float p0 = fmaxf(r0 + a0 * ip, 0.f);
    float p1 = fmaxf(r1 + a1 * ip, 0.f);
    float d0 = p0 * v0[2 * c] + p1 * v0[2 * c + 1];
#pragma unroll
    for (int off = 1; off < 16; off <<= 1) d0 += __shfl_xor(d0, off);
    if (c == 0) s_ap[n] = d0;
}

// layer-2 scalar push: out[dst] += s[src] * inv[dst]
__global__ void scatter1(const float* __restrict__ s, const int* __restrict__ src,
                         const int* __restrict__ dst, const float* __restrict__ inv,
                         float* __restrict__ out, int E)
{
    int e = blockIdx.x * blockDim.x + threadIdx.x;
    if (e < E) {
        int d = dst[e];
        atomicAdd(&out[d], s[src[e]] * inv[d]);
    }
}

extern "C" void kernel_launch(void* const* d_in, const int* in_sizes, int n_in,
                              void* d_out, int out_size, void* d_ws, size_t ws_size,
                              hipStream_t stream)
{
    const float* x_paper  = (const float*)d_in[0];
    const float* x_author = (const float*)d_in[1];
    const int* src_pp = (const int*)d_in[2];
    const int* dst_pp = (const int*)d_in[3];
    const int* src_ap = (const int*)d_in[4];
    const int* dst_ap = (const int*)d_in[5];
    const int* src_pa = (const int*)d_in[6];
    const int* dst_pa = (const int*)d_in[7];
    const float* Wl1_pp = (const float*)d_in[8];
    const float* bl1_pp = (const float*)d_in[9];
    const float* Wr1_pp = (const float*)d_in[10];
    const float* Wl1_ap = (const float*)d_in[11];
    const float* bl1_ap = (const float*)d_in[12];
    const float* Wr1_ap = (const float*)d_in[13];
    const float* Wl1_pa = (const float*)d_in[14];
    const float* bl1_pa = (const float*)d_in[15];
    const float* Wr1_pa = (const float*)d_in[16];
    const float* Wl2_pp = (const float*)d_in[17];
    const float* bl2_pp = (const float*)d_in[18];
    const float* Wr2_pp = (const float*)d_in[19];
    const float* Wl2_ap = (const float*)d_in[20];
    const float* bl2_ap = (const float*)d_in[21];
    const float* Wr2_ap = (const float*)d_in[22];
    const float* W_lin  = (const float*)d_in[23];
    const float* b_lin  = (const float*)d_in[24];

    const int NP = in_sizes[0] / 64;
    const int NA = in_sizes[1] / 64;
    const int E_PP = in_sizes[2];
    const int E_AP = in_sizes[4];
    const int E_PA = in_sizes[6];

    // ---- workspace layout ----
    char* wp = (char*)d_ws;
    int* head_pp = (int*)wp;        wp += (size_t)NP * 4;
    int* head_ap = (int*)wp;        wp += (size_t)NP * 4;
    int* head_pa = (int*)wp;        wp += (size_t)NA * 4;
    // keep 8B alignment for int2 (2*NP+NA ints = 2,000,000 bytes, %8==0)
    int2* ns_pp = (int2*)wp;        wp += (size_t)E_PP * 8;
    int2* ns_ap = (int2*)wp;        wp += (size_t)E_AP * 8;
    int2* ns_pa = (int2*)wp;        wp += (size_t)E_PA * 8;
    ushort_t* h_pp = (ushort_t*)wp; wp += (size_t)NP * 32 * 2;
    ushort_t* h_pa = (ushort_t*)wp; wp += (size_t)NP * 32 * 2;
    ushort_t* h_ap = (ushort_t*)wp; wp += (size_t)NA * 32 * 2;
    float* s_pp   = (float*)wp;     wp += (size_t)NP * 4;
    float* s_ap   = (float*)wp;     wp += (size_t)NA * 4;
    float* inv_pp = (float*)wp;     wp += (size_t)NP * 4;
    float* inv_ap = (float*)wp;     wp += (size_t)NP * 4;
    float* Wn_p   = (float*)wp;     wp += 64 * 64 * 4;
    float* Wn_a   = (float*)wp;     wp += 64 * 32 * 4;
    float* Wr_p   = (float*)wp;     wp += 64 * 32 * 4;
    float* Wr_a   = (float*)wp;     wp += 64 * 32 * 4;
    float* bias_p = (float*)wp;     wp += 32 * 4;
    float* bias_a = (float*)wp;     wp += 32 * 4;
    float* vv     = (float*)wp;     wp += 128 * 4;

    float* out = (float*)d_out;

    // heads = -1 (contiguous at ws start)
    hipMemsetAsync(d_ws, 0xFF, (size_t)(2 * NP + NA) * sizeof(int), stream);

    prep_weights<<<1, 256, 0, stream>>>(
        Wl1_pp, Wr1_pp, Wl1_ap, Wr1_ap, Wl1_pa, Wr1_pa,
        bl1_pp, bl1_ap, bl1_pa,
        Wl2_pp, bl2_pp, Wr2_pp, Wl2_ap, bl2_ap, Wr2_ap,
        W_lin, b_lin, Wn_p, Wn_a, Wr_p, Wr_a, bias_p, bias_a, vv);

    build_ll<<<(E_PP + 255) / 256, 256, 0, stream>>>(src_pp, dst_pp, head_pp, ns_pp, E_PP);
    build_ll<<<(E_AP + 255) / 256, 256, 0, stream>>>(src_ap, dst_ap, head_ap, ns_ap, E_AP);
    build_ll<<<(E_PA + 255) / 256, 256, 0, stream>>>(src_pa, dst_pa, head_pa, ns_pa, E_PA);

    proj_paper<<<(NP + 7) / 8, 256, 0, stream>>>(x_paper, Wn_p, h_pp, h_pa, NP);
    proj_author<<<(NA + 7) / 8, 256, 0, stream>>>(x_author, Wn_a, h_ap, NA);

    pull_paper<<<(NP + 15) / 16, 256, 0, stream>>>(
        x_paper, h_pp, h_ap, head_pp, ns_pp, head_ap, ns_ap,
        Wr_p, bias_p, vv, s_pp, inv_pp, inv_ap, out, NP);
    pull_author<<<(NA + 15) / 16, 256, 0, stream>>>(
        x_author, h_pa, head_pa, ns_pa, Wr_a, bias_a, vv, s_ap, NA);

    scatter1<<<(E_PP + 255) / 256, 256, 0, stream>>>(s_pp, src_pp, dst_pp, inv_pp, out, E_PP);
    scatter1<<<(E_AP + 255) / 256, 256, 0, stream>>>(s_ap, src_ap, dst_ap, inv_ap, out, E_AP);
}